// Round 19
// baseline (45.714 us; speedup 1.0000x reference)
//
#include <hip/hip_runtime.h>
#include <math.h>

#define NB   4
#define SEQN 512
#define SEQM 512
#define QS   256   // Q_SIZE == K_SIZE
#define HH   128   // H
#define DV   256   // D_V
#define BM   (NB * SEQM)   // 2048 global k rows

static constexpr float kPreScale = 2.8853900817779268f;  // 2*log2(e)
static constexpr float kLog2e    = 1.4426950408889634f;

#if __has_builtin(__builtin_amdgcn_exp2f)
__device__ __forceinline__ float fexp2(float x) { return __builtin_amdgcn_exp2f(x); }
#else
__device__ __forceinline__ float fexp2(float x) { return exp2f(x); }
#endif

#if __has_builtin(__builtin_amdgcn_rcpf)
__device__ __forceinline__ float frcp(float x) { return __builtin_amdgcn_rcpf(x); }
#else
__device__ __forceinline__ float frcp(float x) { return 1.0f / x; }
#endif

// Fused q/k projection + EXP precompute (R19: sigmoid form).
// grid: 512 blocks, 512 threads. Block: 8 rows x 128 cols; thread: 2 rows.
// Q output: qE[grow][h] = e^{2q}  (row-major [2048][128])
// K output (chunk-tiled, R17): ktE[c][grow][j] = e^{2k} for h = 8c+j.
__global__ __launch_bounds__(512) void proj_kernel(
    const float* __restrict__ query, const float* __restrict__ key,
    const float* __restrict__ Wq, const float* __restrict__ Wk,
    float* __restrict__ qE, float* __restrict__ ktE) {
  const int t = threadIdx.x;
  const int half = (NB * SEQN) / 8;            // 256
  const bool isK = blockIdx.x >= half;
  const int rb   = isK ? (blockIdx.x - half) : blockIdx.x;
  const float* __restrict__ in = isK ? key : query;
  const float* __restrict__ W  = isK ? Wk  : Wq;
  const int row0 = rb * 8;

  const int j  = t & 127;                                      // output column (h)
  const int r0 = __builtin_amdgcn_readfirstlane((t >> 7) * 2); // wave-uniform -> SGPR

  const float* __restrict__ x0p = in + (size_t)(row0 + r0 + 0) * QS;
  const float* __restrict__ x1p = in + (size_t)(row0 + r0 + 1) * QS;

  float a0 = 0.f, a1 = 0.f;
  for (int k0 = 0; k0 < QS; k0 += 4) {
    const float w0 = W[(k0 + 0) * HH + j];
    const float w1 = W[(k0 + 1) * HH + j];
    const float w2 = W[(k0 + 2) * HH + j];
    const float w3 = W[(k0 + 3) * HH + j];
    const float4 x0 = *reinterpret_cast<const float4*>(x0p + k0);  // s_load
    const float4 x1 = *reinterpret_cast<const float4*>(x1p + k0);
    a0 = fmaf(x0.x, w0, fmaf(x0.y, w1, fmaf(x0.z, w2, fmaf(x0.w, w3, a0))));
    a1 = fmaf(x1.x, w0, fmaf(x1.y, w1, fmaf(x1.z, w2, fmaf(x1.w, w3, a1))));
  }
  float acc[2] = {a0, a1};
#pragma unroll
  for (int r = 0; r < 2; ++r) {
    const float E = fexp2(acc[r] * kPreScale);   // e^{2x}, no clamp needed (d>1)
    const int grow = row0 + r0 + r;
    if (isK) {
      ktE[(((size_t)(j >> 3) * BM) + grow) * 8 + (j & 7)] = E;
    } else {
      qE[(size_t)grow * HH + j] = E;
    }
  }
}

// Fused scores + softmax + PV. R19: sigmoid-PAIR scores — 3 VALU + 0.5 trans
// per element (vs 5.25 VALU for the rational tree). R7-R18 showed the scores
// phase is AT the fp32 VALU roofline (wave64 op = 2 cyc on SIMD-32), so the
// only lever is lane-op count; rcp's run on the trans unit, hidden by other
// waves' VALU. score = -2 * sum_h wv_h/(Eq*Ek+1) (softmax-invariant C dropped).
// grid = NB * (SEQN/8) = 256 blocks, 1024 threads (16 waves), 48 KB LDS.
// Thread: row-pair (t>>8)*2 x m-pair (t&255)*2 -> 4 scores. (R10 geometry.)
__global__ __launch_bounds__(1024) void fused_kernel(
    const float* __restrict__ qE, const float* __restrict__ ktE,
    const float* __restrict__ wv, const float* __restrict__ value,
    float* __restrict__ out) {
  __shared__ float sp[8][SEQM];        // 16 KB: scores then unnormalized p
  __shared__ float pvbuf[4][8][DV];    // 32 KB: PV partial buffers
  __shared__ float rsh[8];             // 1/rowsum

  const int t  = threadIdx.x;            // 0..1023
  const int b  = blockIdx.x >> 6;        // 4 batches x 64 tiles
  const int n0 = (blockIdx.x & 63) * 8;
  const int mslot = t & 255;
  const int m0 = 2 * mslot;
  const int g2 = __builtin_amdgcn_readfirstlane((t >> 8) * 2);

  const float* __restrict__ qb = qE + ((size_t)(b * SEQN + n0 + g2)) * HH;
  const float* __restrict__ kbase = ktE + ((size_t)b * SEQM + m0) * 8;

  float acc[2][2];
  acc[0][0] = 0.f; acc[0][1] = 0.f; acc[1][0] = 0.f; acc[1][1] = 0.f;

  // k prefetch (chunk 0): 16 contiguous floats = {m0: h0-7, m1: h0-7}
  float4 f0 = *reinterpret_cast<const float4*>(kbase + 0);
  float4 f1 = *reinterpret_cast<const float4*>(kbase + 4);
  float4 f2 = *reinterpret_cast<const float4*>(kbase + 8);
  float4 f3 = *reinterpret_cast<const float4*>(kbase + 12);

  for (int c = 0; c < 16; ++c) {
    const int h0 = c * 8;
    float k0a[8], k1a[8];
    k0a[0] = f0.x; k0a[1] = f0.y; k0a[2] = f0.z; k0a[3] = f0.w;
    k0a[4] = f1.x; k0a[5] = f1.y; k0a[6] = f1.z; k0a[7] = f1.w;
    k1a[0] = f2.x; k1a[1] = f2.y; k1a[2] = f2.z; k1a[3] = f2.w;
    k1a[4] = f3.x; k1a[5] = f3.y; k1a[6] = f3.z; k1a[7] = f3.w;
    if (c + 1 < 16) {
      const float* nb = kbase + (size_t)(c + 1) * BM * 8;
      f0 = *reinterpret_cast<const float4*>(nb + 0);
      f1 = *reinterpret_cast<const float4*>(nb + 4);
      f2 = *reinterpret_cast<const float4*>(nb + 8);
      f3 = *reinterpret_cast<const float4*>(nb + 12);
    }
    // wv chunk (wave-uniform s_loads)
    const float4 wva = *reinterpret_cast<const float4*>(wv + h0);
    const float4 wvb = *reinterpret_cast<const float4*>(wv + h0 + 4);
#pragma unroll
    for (int n = 0; n < 2; ++n) {
      const float* qr = qb + n * HH;
      const float4 qa = *reinterpret_cast<const float4*>(qr + h0);      // s_load
      const float4 qc4 = *reinterpret_cast<const float4*>(qr + h0 + 4); // s_load
      const float Eq0 = qa.x,  Eq1 = qa.y,  Eq2 = qa.z,  Eq3 = qa.w;
      const float Eq4 = qc4.x, Eq5 = qc4.y, Eq6 = qc4.z, Eq7 = qc4.w;
#pragma unroll
      for (int mm = 0; mm < 2; ++mm) {
        const float* Ek = (mm == 0) ? k0a : k1a;
        const float d0 = fmaf(Eq0, Ek[0], 1.0f);
        const float d1 = fmaf(Eq1, Ek[1], 1.0f);
        const float d2 = fmaf(Eq2, Ek[2], 1.0f);
        const float d3 = fmaf(Eq3, Ek[3], 1.0f);
        const float d4 = fmaf(Eq4, Ek[4], 1.0f);
        const float d5 = fmaf(Eq5, Ek[5], 1.0f);
        const float d6 = fmaf(Eq6, Ek[6], 1.0f);
        const float d7 = fmaf(Eq7, Ek[7], 1.0f);
        // pair p = (2j,2j+1): wv0/d0 + wv1/d1 = (wv0*d1 + wv1*d0)/(d0*d1)
        const float n01 = fmaf(wva.x, d1, wva.y * d0);
        const float n23 = fmaf(wva.z, d3, wva.w * d2);
        const float n45 = fmaf(wvb.x, d5, wvb.y * d4);
        const float n67 = fmaf(wvb.z, d7, wvb.w * d6);
        float a = acc[n][mm];
        a = fmaf(n01, frcp(d0 * d1), a);
        a = fmaf(n23, frcp(d2 * d3), a);
        a = fmaf(n45, frcp(d4 * d5), a);
        a = fmaf(n67, frcp(d6 * d7), a);
        acc[n][mm] = a;
      }
    }
  }
  sp[g2 + 0][m0 + 0] = -2.0f * acc[0][0];
  sp[g2 + 0][m0 + 1] = -2.0f * acc[0][1];
  sp[g2 + 1][m0 + 0] = -2.0f * acc[1][0];
  sp[g2 + 1][m0 + 1] = -2.0f * acc[1][1];
  __syncthreads();

  // Phase 2: in-wave full-row softmax. wave w: row = w>>1, half = w&1.
  const int wave = t >> 6;
  const int lane = t & 63;
  const int row  = wave >> 1;
  const int hf   = wave & 1;
  float v[8];
  float mx = -1e30f;
#pragma unroll
  for (int i = 0; i < 8; ++i) {
    v[i] = sp[row][lane + 64 * i];     // full row, 8 vals/lane
    mx = fmaxf(mx, v[i]);
  }
#pragma unroll
  for (int off = 32; off > 0; off >>= 1) mx = fmaxf(mx, __shfl_xor(mx, off));
  float p[8];
  float sum = 0.f;
#pragma unroll
  for (int i = 0; i < 8; ++i) {
    p[i] = fexp2((v[i] - mx) * kLog2e);
    sum += p[i];
  }
#pragma unroll
  for (int off = 32; off > 0; off >>= 1) sum += __shfl_xor(sum, off);
  __syncthreads();                      // all row reads done before overwrite
#pragma unroll
  for (int i = 4 * hf; i < 4 * hf + 4; ++i) sp[row][lane + 64 * i] = p[i];
  if (hf == 0 && lane == 0) rsh[row] = frcp(sum);
  __syncthreads();

  // Phase 3: PV. mg = t>>7 (8 groups x 64 m), dp = (t&127)*2 (float2 d-pair).
  const float* __restrict__ vb = value + (size_t)b * SEQM * DV;
  const int dp = (t & 127) * 2;
  const int mg = t >> 7;
  float o[8][2];
#pragma unroll
  for (int n = 0; n < 8; ++n) { o[n][0] = 0.f; o[n][1] = 0.f; }
  const int mbeg = mg * 64;
  for (int mi = 0; mi < 64; mi += 4) {
    const int mq = mbeg + mi;
    const float2 w0 = *reinterpret_cast<const float2*>(vb + (size_t)(mq + 0) * DV + dp);
    const float2 w1 = *reinterpret_cast<const float2*>(vb + (size_t)(mq + 1) * DV + dp);
    const float2 w2 = *reinterpret_cast<const float2*>(vb + (size_t)(mq + 2) * DV + dp);
    const float2 w3 = *reinterpret_cast<const float2*>(vb + (size_t)(mq + 3) * DV + dp);
#pragma unroll
    for (int n = 0; n < 8; ++n) {
      const float4 p4 = *reinterpret_cast<const float4*>(&sp[n][mq]);  // broadcast
      o[n][0] = fmaf(p4.x, w0.x, fmaf(p4.y, w1.x, fmaf(p4.z, w2.x, fmaf(p4.w, w3.x, o[n][0]))));
      o[n][1] = fmaf(p4.x, w0.y, fmaf(p4.y, w1.y, fmaf(p4.z, w2.y, fmaf(p4.w, w3.y, o[n][1]))));
    }
  }
  if (mg >= 4) {
#pragma unroll
    for (int n = 0; n < 8; ++n)
      *reinterpret_cast<float2*>(&pvbuf[mg - 4][n][dp]) = make_float2(o[n][0], o[n][1]);
  }
  __syncthreads();
  if (mg < 4) {
#pragma unroll
    for (int n = 0; n < 8; ++n) {
      float2 prev = *reinterpret_cast<const float2*>(&pvbuf[mg][n][dp]);
      prev.x += o[n][0]; prev.y += o[n][1];
      *reinterpret_cast<float2*>(&pvbuf[mg][n][dp]) = prev;
    }
  }
  __syncthreads();

  // Final: n = t>>7, d = t&127 (and d+128): 2 outputs/thread.
  {
    const int n = t >> 7;
    const int d = t & 127;
    const float rsn = rsh[n];
    float accA = 0.f, accB = 0.f;
#pragma unroll
    for (int g = 0; g < 4; ++g) {
      accA += pvbuf[g][n][d];
      accB += pvbuf[g][n][d + 128];
    }
    const size_t ob = ((size_t)b * SEQN + n0 + n) * DV;
    out[ob + d]       = accA * rsn;
    out[ob + d + 128] = accB * rsn;
  }
}

extern "C" void kernel_launch(void* const* d_in, const int* in_sizes, int n_in,
                              void* d_out, int out_size, void* d_ws, size_t ws_size,
                              hipStream_t stream) {
  const float* query = (const float*)d_in[0];   // (4,512,256)
  const float* key   = (const float*)d_in[1];   // (4,512,256)
  const float* value = (const float*)d_in[2];   // (4,512,256)
  const float* W_q   = (const float*)d_in[3];   // (256,128)
  const float* W_k   = (const float*)d_in[4];   // (256,128)
  const float* W_v   = (const float*)d_in[5];   // (128,)
  float* out = (float*)d_out;                   // (4,512,256) f32

  // Both intermediates in ws (2 MB total) — no d_out aliasing this round
  // (qE row size != out row size, the old parking trick would race).
  float* ktE = (float*)d_ws;                           // [16][2048][8], 1 MB
  float* qE  = ktE + (size_t)16 * BM * 8;              // [2048][128],   1 MB

  proj_kernel<<<2 * (NB * SEQN) / 8, 512, 0, stream>>>(query, key, W_q, W_k, qE, ktE);
  fused_kernel<<<NB * (SEQN / 8), 1024, 0, stream>>>(qE, ktE, W_v, value, out);
}